// Round 6
// baseline (174.437 us; speedup 1.0000x reference)
//
#include <hip/hip_runtime.h>
#include <stdint.h>

#define N      6144
#define F      128
#define D      32
#define H      4
#define HID    128
#define NP1    6145
#define CHK    256
#define NCHK   24      // chunks per head
#define SEGL   96      // rows per scan segment
#define NSEG   64      // segments per head
#define NBLK   768
#define NTHR   256

// ---- flag indices (each flag on its own 64B line in d_ws) ----
#define FA_BASE 0      // 768: GEMM block done
#define FB_BASE 768    // 96:  chunk sorted
#define FC_BASE 864    // 768: rank block done (32 items)
#define FD_BASE 1632   // 256: segment totals published
#define FE_BASE 1888   // 256: segment VEC rows written
#define FF_BASE 2144   // 384: eval partials written
#define NFLAGS  2528
#define FLAG_BYTES (NFLAGS * 64)

// ---- device scratch ----
__device__ float    g_Wh[(size_t)N * HID];
__device__ float    g_es[H * N];
__device__ float    g_ed[H * N];
__device__ uint64_t g_keys[H * N];
__device__ float    g_dsv[H * N];
__device__ int      g_perm[H * N];
__device__ float    g_SEG[H * 66 * NSEG];
__device__ float    g_VEC[(size_t)H * NP1 * 64];  // [h][k][c] c<32: u*wh pfx, c>=32: v*wh pfx
__device__ float    g_SCL[(size_t)H * NP1 * 2];   // [h][k][{u1,v1}]
__device__ float    g_PART[H * 96 * 32];

__device__ __forceinline__ void setflag(unsigned* flags, int idx) {
    __syncthreads();      // all of this block's writes issued & drained
    if (threadIdx.x == 0)
        __hip_atomic_store(&flags[idx * 16], 1u,
                           __ATOMIC_RELEASE, __HIP_MEMORY_SCOPE_AGENT);
}

// Poll cnt write-once flags starting at flag index `base`.
__device__ __forceinline__ void waitflags(const unsigned* flags, int base, int cnt) {
    __shared__ int s_nok;
    unsigned it = 0;
    for (;;) {
        if (threadIdx.x == 0) s_nok = 0;
        __syncthreads();
        int my = 1;
        for (int i = threadIdx.x; i < cnt; i += NTHR)
            my &= (__hip_atomic_load(&flags[(base + i) * 16], __ATOMIC_RELAXED,
                                     __HIP_MEMORY_SCOPE_AGENT) != 0u) ? 1 : 0;
        if (!my) s_nok = 1;            // benign LDS race
        __syncthreads();
        if (s_nok == 0) break;
        __builtin_amdgcn_s_sleep(8);
        if (++it > (1u << 20)) break;  // safety valve (loud failure, never silent hang)
    }
    __builtin_amdgcn_fence(__ATOMIC_ACQUIRE, "agent");
    __syncthreads();
}

__device__ __forceinline__ uint32_t f2mono(float f) {
    uint32_t u = __float_as_uint(f);
    return (u & 0x80000000u) ? ~u : (u | 0x80000000u);
}

union SmemU {
    struct { uint64_t k[CHK]; } p2;
    struct { uint64_t ks[N]; int part[32][8]; } p3;                  // 50176 B
    struct { float whL[SEGL * 33]; float e1[SEGL]; float e2[SEGL];
             int permL[SEGL]; float tile[SEGL * 69]; float offArr[68]; } p4;
    struct { float ds[N]; float hm[HID]; } p5;
};

__global__ __launch_bounds__(NTHR) void mega4(
        const float* __restrict__ x, const float* __restrict__ W,
        const float* __restrict__ a_src, const float* __restrict__ a_dst,
        const float* __restrict__ W_fc, const float* __restrict__ b_fc,
        float* __restrict__ out, unsigned* __restrict__ flags)
{
    __shared__ SmemU sm;
    const int tid = threadIdx.x;
    const int bid = blockIdx.x;
    const int lane = tid & 63;
    const int wv = tid >> 6;

    // ============ Duty A (all 768): Wh = x@W, e_s/e_d ============
    {
        int rg = wv & 1;
        int ch = wv >> 1;
        int row0 = __builtin_amdgcn_readfirstlane(bid * 8 + rg * 4);
        int col = ch * 64 + lane;   // 0..127
        int h = col >> 5;
        const float* __restrict__ xr = x + (size_t)row0 * F;
        const float* __restrict__ Wp = W + h * (F * D) + (col & 31);
        float acc[4] = {0.f, 0.f, 0.f, 0.f};
#pragma unroll 4
        for (int f = 0; f < F; ++f) {
            float w = Wp[f * D];
            acc[0] = fmaf(xr[f], w, acc[0]);
            acc[1] = fmaf(xr[F + f], w, acc[1]);
            acc[2] = fmaf(xr[2 * F + f], w, acc[2]);
            acc[3] = fmaf(xr[3 * F + f], w, acc[3]);
        }
        float as = a_src[col], ad = a_dst[col];
#pragma unroll
        for (int r = 0; r < 4; ++r) {
            int n = row0 + r;
            g_Wh[(size_t)n * HID + col] = acc[r];
            float ts = acc[r] * as, td = acc[r] * ad;
#pragma unroll
            for (int m = 1; m < 32; m <<= 1) {
                ts += __shfl_xor(ts, m);
                td += __shfl_xor(td, m);
            }
            if ((lane & 31) == 0) { g_es[h * N + n] = ts; g_ed[h * N + n] = td; }
        }
        setflag(flags, FA_BASE + bid);
    }

    // ============ Duty B (96 blocks): sort 256-key chunks ============
    if (bid < H * NCHK) {
        waitflags(flags, FA_BASE, NBLK);
        int h = bid / NCHK, c = bid % NCHK;
        int j = c * CHK + tid;
        uint64_t myk = (((uint64_t)f2mono(g_ed[h * N + j])) << 13) | (uint32_t)j;
        sm.p2.k[tid] = myk;
        __syncthreads();
        int rank = 0;
        for (int s2 = 0; s2 < CHK; ++s2)
            rank += (sm.p2.k[s2] < myk) ? 1 : 0;
        g_keys[h * N + c * CHK + rank] = myk;
        setflag(flags, FB_BASE + bid);
    }

    // ============ Duty C (all 768): global rank -> dsv, perm ============
    {
        int h = bid / 192;
        int ibase = (bid % 192) * 32;
        waitflags(flags, FB_BASE + h * NCHK, NCHK);
        const uint64_t* kh = g_keys + (size_t)h * N;
        for (int r = tid; r < N; r += NTHR) sm.p3.ks[r] = kh[r];
        __syncthreads();
        {
            int item = tid & 31, sl = tid >> 5;    // 8 slices x 3 chunks
            int slot = ibase + item;
            uint64_t myk = sm.p3.ks[slot];
            int cown = slot >> 8;
            int cnt = 0;
            for (int cc = sl * 3; cc < sl * 3 + 3; ++cc) {
                if (cc == cown) continue;
                int base = cc * CHK;
                int pos = 0;
#pragma unroll
                for (int st = CHK; st >= 1; st >>= 1) {
                    int np = pos + st;
                    if (np <= CHK && sm.p3.ks[base + np - 1] < myk) pos = np;
                }
                cnt += pos;
            }
            sm.p3.part[item][sl] = cnt;
        }
        __syncthreads();
        if (tid < 32) {
            int slot = ibase + tid;
            uint64_t myk = sm.p3.ks[slot];
            int rank = slot & (CHK - 1);
#pragma unroll
            for (int sl = 0; sl < 8; ++sl) rank += sm.p3.part[tid][sl];
            uint32_t m = (uint32_t)(myk >> 13);
            uint32_t u = (m & 0x80000000u) ? (m ^ 0x80000000u) : ~m;
            g_dsv[h * N + rank] = __uint_as_float(u);
            g_perm[h * N + rank] = (int)(myk & 8191u);
        }
        setflag(flags, FC_BASE + bid);
    }

    // ============ Duty D+E (256 blocks): segment scans + lookback ============
    if (bid < H * NSEG) {
        int h = bid >> 6, seg = bid & 63;
        int r0 = seg * SEGL;
        // need dsv/perm rows r0..r0+95 of head h: rank blocks h*192 + seg*3 ..+2
        waitflags(flags, FC_BASE + h * 192 + seg * 3, 3);
        if (tid < SEGL) {
            sm.p4.permL[tid] = g_perm[h * N + r0 + tid];
            float dv = g_dsv[h * N + r0 + tid];
            sm.p4.e1[tid] = expf(0.01f * dv);
            sm.p4.e2[tid] = expf(dv);
        }
        __syncthreads();
        if (tid < 192) {            // gather Wh rows -> whL[96][33]
            int row = tid >> 1, half = tid & 1;
            int j = sm.p4.permL[row];
            const float4* src = (const float4*)&g_Wh[(size_t)j * HID + h * D + half * 16];
            float4 A = src[0], B = src[1], C = src[2], E = src[3];
            float* w = &sm.p4.whL[row * 33 + half * 16];
            w[0]=A.x; w[1]=A.y; w[2]=A.z; w[3]=A.w;
            w[4]=B.x; w[5]=B.y; w[6]=B.z; w[7]=B.w;
            w[8]=C.x; w[9]=C.y; w[10]=C.z; w[11]=C.w;
            w[12]=E.x; w[13]=E.y; w[14]=E.z; w[15]=E.w;
        }
        __syncthreads();
        for (int k = 0; k < 17; ++k) {
            int c = wv + 4 * k;
            if (c >= 66) break;
            float p_lo, p_hi;
            if (c < 64) {
                int fam = c >> 5, d = c & 31;
                const float* e = fam ? sm.p4.e2 : sm.p4.e1;
                p_lo = e[lane] * sm.p4.whL[lane * 33 + d];
                p_hi = (lane < 32) ? e[64 + lane] * sm.p4.whL[(64 + lane) * 33 + d] : 0.f;
            } else {
                const float* e = (c == 65) ? sm.p4.e2 : sm.p4.e1;
                p_lo = e[lane];
                p_hi = (lane < 32) ? e[64 + lane] : 0.f;
            }
            float s_lo = p_lo;
#pragma unroll
            for (int m = 1; m < 64; m <<= 1) {
                float t = __shfl_up(s_lo, m);
                if (lane >= m) s_lo += t;
            }
            float tot_lo = __shfl(s_lo, 63);
            float s_hi = p_hi;
#pragma unroll
            for (int m = 1; m < 32; m <<= 1) {
                float t = __shfl_up(s_hi, m);
                if (lane >= m) s_hi += t;
            }
            float tot_hi = __shfl(s_hi, 31);
            sm.p4.tile[lane * 69 + c] = s_lo;
            if (lane < 32) sm.p4.tile[(64 + lane) * 69 + c] = tot_lo + s_hi;
            if (lane == 0) g_SEG[(h * 66 + c) * NSEG + seg] = tot_lo + tot_hi;
        }
        setflag(flags, FD_BASE + bid);
        // decoupled lookback: need totals of segments 0..seg-1 of this head
        waitflags(flags, FD_BASE + h * NSEG, seg);
        for (int k = 0; k < 17; ++k) {
            int c = wv + 4 * k;
            if (c >= 66) break;
            float sv = g_SEG[(h * 66 + c) * NSEG + lane];
            float msk = (lane < seg) ? sv : 0.f;
#pragma unroll
            for (int m = 1; m < 64; m <<= 1) msk += __shfl_xor(msk, m);
            if (lane == 0) sm.p4.offArr[c] = msk;
        }
        __syncthreads();
        float* vec = g_VEC + (size_t)h * NP1 * 64;
        for (int t = tid; t < SEGL * 64; t += NTHR) {
            int row = t >> 6, c = t & 63;
            vec[(size_t)(r0 + row + 1) * 64 + c] = sm.p4.tile[row * 69 + c] + sm.p4.offArr[c];
        }
        float* scl = g_SCL + (size_t)h * NP1 * 2;
        for (int t = tid; t < SEGL * 2; t += NTHR) {
            int row = t >> 1, c = t & 1;
            scl[(size_t)(r0 + row + 1) * 2 + c] = sm.p4.tile[row * 69 + 64 + c] + sm.p4.offArr[64 + c];
        }
        if (seg == 0) {
            if (tid < 64) vec[tid] = 0.f;
            else if (tid < 66) scl[tid - 64] = 0.f;
        }
        setflag(flags, FE_BASE + bid);
    }

    // ============ Duty F (384 blocks): eval ============
    if (bid < H * 96) {
        int h = bid / 96;
        int ibase = (bid % 96) * 64;
        waitflags(flags, FE_BASE + h * NSEG, NSEG);
        for (int r = tid; r < N; r += NTHR) sm.p5.ds[r] = g_dsv[h * N + r];
        __syncthreads();
        const float* vec = g_VEC + (size_t)h * NP1 * 64;
        const float* scl = g_SCL + (size_t)h * NP1 * 2;
        int q = wv;
        float vt[8];
#pragma unroll
        for (int j = 0; j < 8; ++j) vt[j] = vec[(size_t)N * 64 + 32 + q * 8 + j];
        float v1T = scl[(size_t)N * 2 + 1];

        int i = ibase + lane;
        float s = g_es[h * N + i];
        float nst = -s;
        int k = 0;
#pragma unroll
        for (int st = 4096; st >= 1; st >>= 1) {
            int np = k + st;
            if (np <= N && sm.p5.ds[np - 1] <= nst) k = np;
        }
        float e1 = expf(0.01f * s), e2 = expf(s);
        float pu1 = scl[(size_t)k * 2 + 0];
        float pv1 = scl[(size_t)k * 2 + 1];
        float inv = 1.0f / (e1 * pu1 + e2 * (v1T - pv1));
        const float4* U = (const float4*)&vec[(size_t)k * 64 + q * 8];
        const float4* V = (const float4*)&vec[(size_t)k * 64 + 32 + q * 8];
        float4 u0 = U[0], u1 = U[1], v0 = V[0], v1 = V[1];
        float uu[8] = {u0.x,u0.y,u0.z,u0.w,u1.x,u1.y,u1.z,u1.w};
        float vv[8] = {v0.x,v0.y,v0.z,v0.w,v1.x,v1.y,v1.z,v1.w};
        float acc[8];
#pragma unroll
        for (int j = 0; j < 8; ++j) {
            float num = e1 * uu[j] + e2 * (vt[j] - vv[j]);
            acc[j] = fmaxf(num, 0.f) * inv;     // relu(elu(x)) == relu(x); denom > 0
        }
#pragma unroll
        for (int j = 0; j < 8; ++j) {
#pragma unroll
            for (int m = 1; m < 64; m <<= 1) acc[j] += __shfl_xor(acc[j], m);
        }
        if (lane == 0) {
#pragma unroll
            for (int j = 0; j < 8; ++j)
                g_PART[bid * 32 + q * 8 + j] = acc[j];
        }
        setflag(flags, FF_BASE + bid);
    }

    // ============ Duty G (block 0): finalize ============
    if (bid == 0) {
        waitflags(flags, FF_BASE, H * 96);
        if (tid < HID) {
            int hh = tid >> 5, dd = tid & 31;
            float sum = 0.f;
            for (int s2 = 0; s2 < 96; ++s2)
                sum += g_PART[(hh * 96 + s2) * 32 + dd];
            sm.p5.hm[tid] = sum * (1.0f / (float)N);
        }
        __syncthreads();
        if (tid < 128) {
            float y = b_fc[tid];
#pragma unroll 8
            for (int c = 0; c < 128; ++c)
                y = fmaf(sm.p5.hm[c], W_fc[c * 128 + tid], y);
            out[tid] = y;
        }
    }
}

extern "C" void kernel_launch(void* const* d_in, const int* in_sizes, int n_in,
                              void* d_out, int out_size, void* d_ws, size_t ws_size,
                              hipStream_t stream) {
    (void)in_sizes; (void)n_in; (void)ws_size; (void)out_size;
    const float* x     = (const float*)d_in[0];
    const float* W     = (const float*)d_in[1];
    const float* a_src = (const float*)d_in[2];
    const float* a_dst = (const float*)d_in[3];
    const float* W_fc  = (const float*)d_in[4];
    const float* b_fc  = (const float*)d_in[5];
    float* out = (float*)d_out;
    unsigned* flags = (unsigned*)d_ws;

    // clear all dataflow flags in stream order (race-free across graph replays)
    hipMemsetAsync(flags, 0, FLAG_BYTES, stream);
    mega4<<<dim3(NBLK), dim3(NTHR), 0, stream>>>(x, W, a_src, a_dst, W_fc, b_fc, out, flags);
}

// Round 7
// 133.486 us; speedup vs baseline: 1.3068x; 1.3068x over previous
//
#include <hip/hip_runtime.h>
#include <stdint.h>

#define N      6144
#define F      128
#define D      32
#define H      4
#define HID    128
#define BINS   4096
#define RLO    (-6.0f)
#define INVW   (BINS / 12.0f)
#define NC     68          // 66 used components, padded to 68 (17 float4)
#define NROWS  (BINS + 1)

// binacc: [h][c][b] column-major for scan; pref: [h][row][c] row-major for eval
#define BINACC_FLOATS ((size_t)H * NC * BINS)
#define PREF_FLOATS   ((size_t)H * NROWS * NC)
#define BINACC_BYTES  (BINACC_FLOATS * 4)

__device__ float g_es[H * N];
__device__ float g_PART[96 * 32];

// ============ K1: GEMM (register-resident Wh) + e_s store + fused binning ============
__global__ __launch_bounds__(256) void k1_gemm_bin(const float* __restrict__ x,
                                                   const float* __restrict__ W,
                                                   const float* __restrict__ a_src,
                                                   const float* __restrict__ a_dst,
                                                   float* __restrict__ binacc) {
    int tid  = threadIdx.x;
    int wv   = tid >> 6;
    int lane = tid & 63;
    int rg   = wv & 1;
    int ch   = wv >> 1;
    int row0 = __builtin_amdgcn_readfirstlane(blockIdx.x * 8 + rg * 4);
    int col  = ch * 64 + lane;     // 0..127
    int h    = col >> 5;
    int d    = col & 31;
    const float* __restrict__ xr = x + (size_t)row0 * F;
    const float* __restrict__ Wp = W + h * (F * D) + d;
    float acc[4] = {0.f, 0.f, 0.f, 0.f};
#pragma unroll 4
    for (int f = 0; f < F; ++f) {
        float w = Wp[f * D];
        acc[0] = fmaf(xr[f],         w, acc[0]);
        acc[1] = fmaf(xr[F + f],     w, acc[1]);
        acc[2] = fmaf(xr[2 * F + f], w, acc[2]);
        acc[3] = fmaf(xr[3 * F + f], w, acc[3]);
    }
    float as = a_src[col], ad = a_dst[col];
    float* hb = binacc + (size_t)h * NC * BINS;
#pragma unroll
    for (int r = 0; r < 4; ++r) {
        int n = row0 + r;
        float ts = acc[r] * as, td = acc[r] * ad;
#pragma unroll
        for (int m = 1; m < 32; m <<= 1) {
            ts += __shfl_xor(ts, m);
            td += __shfl_xor(td, m);
        }
        // all 32 lanes of the head-group now hold the full e_s/e_d sums
        if ((lane & 31) == 0) g_es[h * N + n] = ts;
        float e1 = expf(0.01f * td);
        float e2 = expf(td);
        int b = (int)floorf((td - RLO) * INVW);
        b = min(max(b, 0), BINS - 1);
        // lane d holds Wh[n][h*32+d] == acc[r]
        atomicAdd(hb + (size_t)d * BINS + b,        e1 * acc[r]);
        atomicAdd(hb + (size_t)(32 + d) * BINS + b, e2 * acc[r]);
        if ((lane & 31) == 0) {
            atomicAdd(hb + (size_t)64 * BINS + b, e1);
            atomicAdd(hb + (size_t)65 * BINS + b, e2);
        }
    }
}

// ============ K2: 264 exclusive scans (binacc columns -> pref rows) ============
__global__ __launch_bounds__(256) void k2_scan(const float* __restrict__ binacc,
                                               float* __restrict__ pref) {
    __shared__ float tsum[256];
    int bidx = blockIdx.x;             // H*66
    int h = bidx / 66, c = bidx % 66;
    int tid = threadIdx.x;
    const float* src = binacc + ((size_t)h * NC + c) * BINS;
    int t0 = tid * 16;
    float v[16];
    const float4* s4 = (const float4*)(src + t0);
#pragma unroll
    for (int g = 0; g < 4; ++g) {
        float4 q = s4[g];
        v[g * 4 + 0] = q.x; v[g * 4 + 1] = q.y;
        v[g * 4 + 2] = q.z; v[g * 4 + 3] = q.w;
    }
    float run = 0.f;
    float incl[16];
#pragma unroll
    for (int j = 0; j < 16; ++j) { run += v[j]; incl[j] = run; }
    tsum[tid] = run;
    for (int off = 1; off < 256; off <<= 1) {
        __syncthreads();
        float t = (tid >= off) ? tsum[tid - off] : 0.f;
        __syncthreads();
        tsum[tid] += t;
    }
    float offset = tsum[tid] - run;    // exclusive offset for this thread
    float* dst = pref + (size_t)h * NROWS * NC + c;
    if (tid == 0) dst[0] = 0.f;
#pragma unroll
    for (int j = 0; j < 16; ++j)
        dst[(size_t)(t0 + j + 1) * NC] = offset + incl[j];
}

// ============ K3: eval — direct bin index, one row read, block reduce ============
__global__ __launch_bounds__(256) void k3_eval(const float* __restrict__ pref) {
    __shared__ float tot[NC];
    __shared__ float wred[4][32];
    int bidx = blockIdx.x;             // 96 = H*24
    int h = bidx / 24;
    int tid = threadIdx.x;
    int lane = tid & 63, wv = tid >> 6;
    const float* hp = pref + (size_t)h * NROWS * NC;
    if (tid < NC) tot[tid] = hp[(size_t)BINS * NC + tid];
    __syncthreads();

    int i = (bidx % 24) * 256 + tid;
    float s = g_es[h * N + i];
    float th = -s;
    int idx = (int)floorf((th - RLO) * INVW);
    int row = min(max(idx + 1, 0), BINS);
    const float4* rp4 = (const float4*)(hp + (size_t)row * NC);
    float e1 = expf(0.01f * s), e2 = expf(s);
    float4 sc = rp4[16];               // c=64..67 (64=u1, 65=v1)
    float denom = e1 * sc.x + e2 * (tot[65] - sc.y);
    float inv = 1.0f / denom;

    float av[32];
#pragma unroll
    for (int g = 0; g < 8; ++g) {
        float4 u4 = rp4[g];
        float4 v4 = rp4[8 + g];
        float us[4] = {u4.x, u4.y, u4.z, u4.w};
        float vs[4] = {v4.x, v4.y, v4.z, v4.w};
#pragma unroll
        for (int k = 0; k < 4; ++k) {
            int dd = g * 4 + k;
            float num = e1 * us[k] + e2 * (tot[32 + dd] - vs[k]);
            av[dd] = fmaxf(num, 0.f) * inv;   // relu(elu(x)) == relu(x); denom > 0
        }
    }
#pragma unroll
    for (int dd = 0; dd < 32; ++dd) {
#pragma unroll
        for (int m = 1; m < 64; m <<= 1) av[dd] += __shfl_xor(av[dd], m);
    }
    if (lane == 0) {
#pragma unroll
        for (int dd = 0; dd < 32; ++dd) wred[wv][dd] = av[dd];
    }
    __syncthreads();
    if (tid < 32)
        g_PART[bidx * 32 + tid] =
            wred[0][tid] + wred[1][tid] + wred[2][tid] + wred[3][tid];
}

// ============ K4: mean + final linear ============
__global__ __launch_bounds__(128) void k4_out(const float* __restrict__ W_fc,
                                              const float* __restrict__ b_fc,
                                              float* __restrict__ out) {
    __shared__ float hm[128];
    int tid = threadIdx.x;
    {
        int hh = tid >> 5, dd = tid & 31;
        float sum = 0.f;
        for (int ch = 0; ch < 24; ++ch)
            sum += g_PART[((hh * 24 + ch) * 32) + dd];
        hm[tid] = sum * (1.0f / (float)N);
    }
    __syncthreads();
    float y = b_fc[tid];
#pragma unroll 8
    for (int c = 0; c < 128; ++c)
        y = fmaf(hm[c], W_fc[c * 128 + tid], y);
    out[tid] = y;
}

extern "C" void kernel_launch(void* const* d_in, const int* in_sizes, int n_in,
                              void* d_out, int out_size, void* d_ws, size_t ws_size,
                              hipStream_t stream) {
    (void)in_sizes; (void)n_in; (void)ws_size; (void)out_size;
    const float* x     = (const float*)d_in[0];
    const float* W     = (const float*)d_in[1];
    const float* a_src = (const float*)d_in[2];
    const float* a_dst = (const float*)d_in[3];
    const float* W_fc  = (const float*)d_in[4];
    const float* b_fc  = (const float*)d_in[5];
    float* out = (float*)d_out;

    float* binacc = (float*)d_ws;                      // 4.46 MB
    float* pref   = (float*)d_ws + BINACC_FLOATS;      // 4.46 MB

    hipMemsetAsync(binacc, 0, BINACC_BYTES, stream);
    k1_gemm_bin<<<dim3(N / 8), dim3(256), 0, stream>>>(x, W, a_src, a_dst, binacc);
    k2_scan<<<dim3(H * 66), dim3(256), 0, stream>>>(binacc, pref);
    k3_eval<<<dim3(96), dim3(256), 0, stream>>>(pref);
    k4_out<<<dim3(1), dim3(128), 0, stream>>>(W_fc, b_fc, out);
}

// Round 8
// 57.414 us; speedup vs baseline: 3.0382x; 2.3250x over previous
//
#include <hip/hip_runtime.h>
#include <stdint.h>

#define N      6144
#define F      128
#define D      32
#define H      4
#define HID    128
#define BINS   4096
#define RLO    (-6.0f)
#define INVW   (BINS / 12.0f)
#define NC     68          // 66 used components, padded to 68 (17 float4)
#define NROWS  (BINS + 1)

// ---- device scratch ----
__device__ __align__(16) float g_wht[(size_t)H * D * N];   // [h*32+d][N]
__device__ float g_es[H * N];
__device__ float g_e1[H * N];
__device__ float g_e2[H * N];
__device__ int   g_bin[H * N];
__device__ __align__(16) float g_pref[(size_t)H * NROWS * NC];
__device__ float g_PART[96 * 32];

// ============ K1: pure GEMM -> WhT, es, e1/e2/bin (no atomics) ============
__global__ __launch_bounds__(256) void k1_gemm(const float* __restrict__ x,
                                               const float* __restrict__ W,
                                               const float* __restrict__ a_src,
                                               const float* __restrict__ a_dst) {
    int tid  = threadIdx.x;
    int wv   = tid >> 6;
    int lane = tid & 63;
    int rg   = wv & 1;
    int ch   = wv >> 1;
    int row0 = __builtin_amdgcn_readfirstlane(blockIdx.x * 8 + rg * 4);
    int col  = ch * 64 + lane;     // 0..127
    int h    = col >> 5;
    int d    = col & 31;
    const float* __restrict__ xr = x + (size_t)row0 * F;
    const float* __restrict__ Wp = W + h * (F * D) + d;
    float acc[4] = {0.f, 0.f, 0.f, 0.f};
#pragma unroll 4
    for (int f = 0; f < F; ++f) {
        float w = Wp[f * D];
        acc[0] = fmaf(xr[f],         w, acc[0]);
        acc[1] = fmaf(xr[F + f],     w, acc[1]);
        acc[2] = fmaf(xr[2 * F + f], w, acc[2]);
        acc[3] = fmaf(xr[3 * F + f], w, acc[3]);
    }
    float as = a_src[col], ad = a_dst[col];
#pragma unroll
    for (int r = 0; r < 4; ++r) {
        int n = row0 + r;
        float ts = acc[r] * as, td = acc[r] * ad;
#pragma unroll
        for (int m = 1; m < 32; m <<= 1) {
            ts += __shfl_xor(ts, m);
            td += __shfl_xor(td, m);
        }
        if ((lane & 31) == 0) {
            g_es[h * N + n] = ts;
            float e1 = expf(0.01f * td);
            float e2 = expf(td);
            g_e1[h * N + n] = e1;
            g_e2[h * N + n] = e2;
            int b = (int)floorf((td - RLO) * INVW);
            g_bin[h * N + n] = min(max(b, 0), BINS - 1);
        }
    }
    float4 w4;
    w4.x = acc[0]; w4.y = acc[1]; w4.z = acc[2]; w4.w = acc[3];
    *(float4*)&g_wht[(size_t)(h * 32 + d) * N + row0] = w4;
}

// ============ K2: per-(h,c) LDS histogram + fused exclusive scan ============
__global__ __launch_bounds__(256) void k2_bin_scan() {
    __shared__ float bins[BINS];     // 16 KB private histogram
    __shared__ float tsum[256];
    int bidx = blockIdx.x;           // H*66
    int h = bidx / 66, c = bidx % 66;
    int tid = threadIdx.x;
    for (int i = tid; i < BINS; i += 256) bins[i] = 0.f;
    __syncthreads();

    const int*   bi = g_bin + h * N;
    const float* ev = (((c < 32) || (c == 64)) ? g_e1 : g_e2) + h * N;
    if (c < 64) {
        const float* wcol = g_wht + (size_t)(h * 32 + (c & 31)) * N;
        for (int n = tid; n < N; n += 256)
            atomicAdd(&bins[bi[n]], ev[n] * wcol[n]);
    } else {
        for (int n = tid; n < N; n += 256)
            atomicAdd(&bins[bi[n]], ev[n]);
    }
    __syncthreads();

    // exclusive scan of bins -> pref[h][b+1][c], pref[h][0][c] = 0
    int t0 = tid * 16;
    float incl[16];
    float run = 0.f;
#pragma unroll
    for (int j = 0; j < 16; ++j) { run += bins[t0 + j]; incl[j] = run; }
    tsum[tid] = run;
    for (int off = 1; off < 256; off <<= 1) {
        __syncthreads();
        float t = (tid >= off) ? tsum[tid - off] : 0.f;
        __syncthreads();
        tsum[tid] += t;
    }
    float offset = tsum[tid] - run;
    float* dst = g_pref + (size_t)h * NROWS * NC + c;
    if (tid == 0) dst[0] = 0.f;
#pragma unroll
    for (int j = 0; j < 16; ++j)
        dst[(size_t)(t0 + j + 1) * NC] = offset + incl[j];
}

// ============ K3: eval — direct bin index, one row read, block reduce ============
__global__ __launch_bounds__(256) void k3_eval() {
    __shared__ float tot[NC];
    __shared__ float wred[4][32];
    int bidx = blockIdx.x;             // 96 = H*24
    int h = bidx / 24;
    int tid = threadIdx.x;
    int lane = tid & 63, wv = tid >> 6;
    const float* hp = g_pref + (size_t)h * NROWS * NC;
    if (tid < NC) tot[tid] = hp[(size_t)BINS * NC + tid];
    __syncthreads();

    int i = (bidx % 24) * 256 + tid;
    float s = g_es[h * N + i];
    float th = -s;
    int idx = (int)floorf((th - RLO) * INVW);
    int row = min(max(idx + 1, 0), BINS);
    const float4* rp4 = (const float4*)(hp + (size_t)row * NC);
    float e1 = expf(0.01f * s), e2 = expf(s);
    float4 sc = rp4[16];               // c=64..67 (64=u1, 65=v1)
    float denom = e1 * sc.x + e2 * (tot[65] - sc.y);
    float inv = 1.0f / denom;

    float av[32];
#pragma unroll
    for (int g = 0; g < 8; ++g) {
        float4 u4 = rp4[g];
        float4 v4 = rp4[8 + g];
        float us[4] = {u4.x, u4.y, u4.z, u4.w};
        float vs[4] = {v4.x, v4.y, v4.z, v4.w};
#pragma unroll
        for (int k = 0; k < 4; ++k) {
            int dd = g * 4 + k;
            float num = e1 * us[k] + e2 * (tot[32 + dd] - vs[k]);
            av[dd] = fmaxf(num, 0.f) * inv;   // relu(elu(x)) == relu(x); denom > 0
        }
    }
#pragma unroll
    for (int dd = 0; dd < 32; ++dd) {
#pragma unroll
        for (int m = 1; m < 64; m <<= 1) av[dd] += __shfl_xor(av[dd], m);
    }
    if (lane == 0) {
#pragma unroll
        for (int dd = 0; dd < 32; ++dd) wred[wv][dd] = av[dd];
    }
    __syncthreads();
    if (tid < 32)
        g_PART[bidx * 32 + tid] =
            wred[0][tid] + wred[1][tid] + wred[2][tid] + wred[3][tid];
}

// ============ K4: mean + final linear ============
__global__ __launch_bounds__(128) void k4_out(const float* __restrict__ W_fc,
                                              const float* __restrict__ b_fc,
                                              float* __restrict__ out) {
    __shared__ float hm[128];
    int tid = threadIdx.x;
    {
        int hh = tid >> 5, dd = tid & 31;
        float sum = 0.f;
        for (int ch = 0; ch < 24; ++ch)
            sum += g_PART[((hh * 24 + ch) * 32) + dd];
        hm[tid] = sum * (1.0f / (float)N);
    }
    __syncthreads();
    float y = b_fc[tid];
#pragma unroll 8
    for (int c = 0; c < 128; ++c)
        y = fmaf(hm[c], W_fc[c * 128 + tid], y);
    out[tid] = y;
}

extern "C" void kernel_launch(void* const* d_in, const int* in_sizes, int n_in,
                              void* d_out, int out_size, void* d_ws, size_t ws_size,
                              hipStream_t stream) {
    (void)in_sizes; (void)n_in; (void)d_ws; (void)ws_size; (void)out_size;
    const float* x     = (const float*)d_in[0];
    const float* W     = (const float*)d_in[1];
    const float* a_src = (const float*)d_in[2];
    const float* a_dst = (const float*)d_in[3];
    const float* W_fc  = (const float*)d_in[4];
    const float* b_fc  = (const float*)d_in[5];
    float* out = (float*)d_out;

    k1_gemm<<<dim3(N / 8), dim3(256), 0, stream>>>(x, W, a_src, a_dst);
    k2_bin_scan<<<dim3(H * 66), dim3(256), 0, stream>>>();
    k3_eval<<<dim3(96), dim3(256), 0, stream>>>();
    k4_out<<<dim3(1), dim3(128), 0, stream>>>(W_fc, b_fc, out);
}